// Round 4
// baseline (2307.189 us; speedup 1.0000x reference)
//
#include <hip/hip_runtime.h>
#include <hip/hip_cooperative_groups.h>
#include <cstdint>

namespace cg = cooperative_groups;

#define N_NODES 50000
#define N_EDGES 800000
#define IN_DIM  256
#define HID     128
#define T_STEPS 8

// ---------- float <-> orderable uint encoding for atomic min/max ----------
static __device__ __forceinline__ unsigned int enc_f(float f) {
    unsigned int u = __float_as_uint(f);
    return (u & 0x80000000u) ? ~u : (u | 0x80000000u);
}
static __device__ __forceinline__ float dec_f(unsigned int u) {
    unsigned int b = (u & 0x80000000u) ? (u ^ 0x80000000u) : ~u;
    return __uint_as_float(b);
}

// ---------- CSR build ----------
__global__ void k_count(const int* __restrict__ dst, int* __restrict__ counts) {
    int e = blockIdx.x * blockDim.x + threadIdx.x;
    if (e < N_EDGES) atomicAdd(&counts[dst[e]], 1);
}

__global__ void k_scan1(const int* __restrict__ counts, int* __restrict__ row_tmp,
                        int* __restrict__ blocksum) {
    __shared__ int sh[256];
    int t = threadIdx.x, i = blockIdx.x * 256 + t;
    int c = (i < N_NODES) ? counts[i] : 0;
    sh[t] = c; __syncthreads();
    for (int off = 1; off < 256; off <<= 1) {
        int val = (t >= off) ? sh[t - off] : 0;
        __syncthreads();
        sh[t] += val;
        __syncthreads();
    }
    if (i < N_NODES) row_tmp[i] = sh[t] - c;     // exclusive
    if (t == 255) blocksum[blockIdx.x] = sh[255];
}

__global__ void k_scan2(const int* __restrict__ blocksum, int* __restrict__ blockoff,
                        int nb, int* __restrict__ row_ptr) {
    if (threadIdx.x == 0) {
        int acc = 0;
        for (int b = 0; b < nb; ++b) { blockoff[b] = acc; acc += blocksum[b]; }
        row_ptr[N_NODES] = acc;   // == N_EDGES
    }
}

__global__ void k_scan3(const int* __restrict__ row_tmp, const int* __restrict__ blockoff,
                        int* __restrict__ row_ptr) {
    int i = blockIdx.x * blockDim.x + threadIdx.x;
    if (i < N_NODES) row_ptr[i] = row_tmp[i] + blockoff[i >> 8];
}

// fill CSR slots directly with the (eid, src, attr) triple (arbitrary order)
__global__ void k_fill(const int* __restrict__ dst, const int* __restrict__ src,
                       const float* __restrict__ attr,
                       const int* __restrict__ row_ptr, int* __restrict__ cursor,
                       int* __restrict__ eid, int* __restrict__ src_s,
                       float* __restrict__ attr_s) {
    int e = blockIdx.x * blockDim.x + threadIdx.x;
    if (e >= N_EDGES) return;
    int d = dst[e];
    int p = row_ptr[d] + atomicAdd(&cursor[d], 1);
    eid[p]    = e;
    src_s[p]  = src[e];
    attr_s[p] = attr[e];
}

// wave-wide bitonic sort per node by eid: restores np.add.at ascending order
__global__ __launch_bounds__(256) void k_bsort(const int* __restrict__ row_ptr,
                                               int* __restrict__ eid,
                                               int* __restrict__ src_s,
                                               float* __restrict__ attr_s) {
    int node = blockIdx.x * 4 + (threadIdx.x >> 6);
    int l = threadIdx.x & 63;
    int beg = row_ptr[node], end = row_ptr[node + 1], cnt = end - beg;
    if (cnt <= 1) return;
    if (cnt <= 64) {
        int key = 0x7FFFFFFF, sv = 0; float av = 0.f;
        if (l < cnt) { key = eid[beg + l]; sv = src_s[beg + l]; av = attr_s[beg + l]; }
        #pragma unroll
        for (int k = 2; k <= 64; k <<= 1) {
            for (int j = k >> 1; j > 0; j >>= 1) {
                int   pk = __shfl_xor(key, j);
                int   ps = __shfl_xor(sv, j);
                float pa = __shfl_xor(av, j);
                bool lower = (l & j) == 0;
                bool asc   = (l & k) == 0;
                bool take_min = (lower == asc);
                bool take = take_min ? (pk < key) : (pk > key);
                if (take) { key = pk; sv = ps; av = pa; }
            }
        }
        if (l < cnt) { eid[beg + l] = key; src_s[beg + l] = sv; attr_s[beg + l] = av; }
    } else if (l == 0) {
        for (int i = beg + 1; i < end; ++i) {
            int ke = eid[i]; int ks = src_s[i]; float ka = attr_s[i];
            int m = i - 1;
            while (m >= beg && eid[m] > ke) {
                eid[m+1] = eid[m]; src_s[m+1] = src_s[m]; attr_s[m+1] = attr_s[m]; --m;
            }
            eid[m+1] = ke; src_s[m+1] = ks; attr_s[m+1] = ka;
        }
    }
}

// ---------- tiled GEMM: 64 nodes x 128 feats per block, fused min/max ----------
__global__ __launch_bounds__(256) void k_gemm(const float* __restrict__ x,
                                              const float* __restrict__ W,
                                              const float* __restrict__ b,
                                              float* __restrict__ h,
                                              unsigned int* __restrict__ mn_e,
                                              unsigned int* __restrict__ mx_e) {
    __shared__ float Ws[32 * 128];
    __shared__ float xs[64 * 36];
    __shared__ float red_mn[8 * 128];
    __shared__ float red_mx[8 * 128];
    const int tid = threadIdx.x;
    const int n0 = blockIdx.x * 64;
    const int jt = tid & 31, nt = tid >> 5;
    const int j0 = jt * 4;

    float acc[8][4];
    #pragma unroll
    for (int a = 0; a < 8; ++a)
        #pragma unroll
        for (int c = 0; c < 4; ++c) acc[a][c] = 0.0f;

    const int ldn = tid >> 2;
    const int kq  = (tid & 3) * 8;
    const int xrow = (n0 + ldn < N_NODES) ? (n0 + ldn) : (N_NODES - 1);
    const float* xg = x + (size_t)xrow * IN_DIM;

    for (int kc = 0; kc < IN_DIM; kc += 32) {
        __syncthreads();
        float4 xa = *(const float4*)(xg + kc + kq);
        float4 xb = *(const float4*)(xg + kc + kq + 4);
        *(float4*)&xs[ldn * 36 + kq]     = xa;
        *(float4*)&xs[ldn * 36 + kq + 4] = xb;
        #pragma unroll
        for (int p = 0; p < 4; ++p) {
            int r = nt + p * 8;
            *(float4*)&Ws[r * 128 + j0] =
                *(const float4*)(W + (size_t)(kc + r) * HID + j0);
        }
        __syncthreads();
        const float* xbase = &xs[nt * 8 * 36];
        #pragma unroll 4
        for (int k = 0; k < 32; ++k) {
            float4 wf = *(const float4*)&Ws[k * 128 + j0];
            #pragma unroll
            for (int ni = 0; ni < 8; ++ni) {
                float xv = xbase[ni * 36 + k];
                acc[ni][0] = __fmaf_rn(xv, wf.x, acc[ni][0]);
                acc[ni][1] = __fmaf_rn(xv, wf.y, acc[ni][1]);
                acc[ni][2] = __fmaf_rn(xv, wf.z, acc[ni][2]);
                acc[ni][3] = __fmaf_rn(xv, wf.w, acc[ni][3]);
            }
        }
    }

    float4 bv = *(const float4*)(b + j0);
    float lmn[4], lmx[4];
    #pragma unroll
    for (int c = 0; c < 4; ++c) { lmn[c] = INFINITY; lmx[c] = -INFINITY; }
    #pragma unroll
    for (int ni = 0; ni < 8; ++ni) {
        acc[ni][0] = __fadd_rn(acc[ni][0], bv.x);
        acc[ni][1] = __fadd_rn(acc[ni][1], bv.y);
        acc[ni][2] = __fadd_rn(acc[ni][2], bv.z);
        acc[ni][3] = __fadd_rn(acc[ni][3], bv.w);
        #pragma unroll
        for (int c = 0; c < 4; ++c) {
            lmn[c] = fminf(lmn[c], acc[ni][c]);
            lmx[c] = fmaxf(lmx[c], acc[ni][c]);
        }
    }
    #pragma unroll
    for (int c = 0; c < 4; ++c) {
        red_mn[nt * 128 + j0 + c] = lmn[c];
        red_mx[nt * 128 + j0 + c] = lmx[c];
    }
    __syncthreads();
    if (tid < 128) {
        float mnv = red_mn[tid], mxv = red_mx[tid];
        #pragma unroll
        for (int r = 1; r < 8; ++r) {
            mnv = fminf(mnv, red_mn[r * 128 + tid]);
            mxv = fmaxf(mxv, red_mx[r * 128 + tid]);
        }
        atomicMin(&mn_e[tid], enc_f(mnv));
        atomicMax(&mx_e[tid], enc_f(mxv));
    }
    #pragma unroll
    for (int ni = 0; ni < 8; ++ni) {
        int n = n0 + nt * 8 + ni;
        if (n < N_NODES)
            *(float4*)&h[(size_t)n * HID + j0] =
                make_float4(acc[ni][0], acc[ni][1], acc[ni][2], acc[ni][3]);
    }
}

// ---------- init spike bitmask ----------
__global__ void k_init_bits(const int* __restrict__ spike_node, uint32_t* __restrict__ sb) {
    int n = blockIdx.x * blockDim.x + threadIdx.x;
    if (n >= N_NODES) return;
    uint32_t f = spike_node[n] ? 0xFFFFFFFFu : 0u;
    sb[(size_t)n * 4 + 0] = f;
    sb[(size_t)n * 4 + 1] = f;
    sb[(size_t)n * 4 + 2] = f;
    sb[(size_t)n * 4 + 3] = f;
}

// ---------- fallback per-step kernel (verified in R2) ----------
__global__ __launch_bounds__(128) void k_step(const int* __restrict__ row_ptr,
                                              const int* __restrict__ src_s,
                                              const float* __restrict__ attr_s,
                                              const uint32_t* __restrict__ sb_cur,
                                              uint32_t* __restrict__ sb_nxt,
                                              float* __restrict__ h,
                                              float* __restrict__ v,
                                              unsigned char* __restrict__ refc,
                                              const unsigned int* __restrict__ mn_e,
                                              const unsigned int* __restrict__ mx_e,
                                              float* __restrict__ out_spk,
                                              float* __restrict__ out_fus,
                                              int t0, int is_last) {
    __shared__ float    attr_l[4][128];
    __shared__ uint32_t words_l[4][128][4];
    __shared__ uint32_t sbw[16];
    __shared__ int      rp[5];

    const int tid = threadIdx.x;
    const int ns = tid >> 5, ln = tid & 31;
    const int nb = blockIdx.x * 4;
    const int n  = nb + ns;

    if (tid < 16) sbw[tid] = 0;
    if (tid < 5)  rp[tid] = row_ptr[nb + tid];
    __syncthreads();

    const int beg = rp[ns], cnt = rp[ns + 1] - beg;
    int cmax = 0;
    #pragma unroll
    for (int q = 0; q < 4; ++q) cmax = max(cmax, rp[q + 1] - rp[q]);
    const int nchunk = (cmax + 127) >> 7;

    float agg0 = 0.f, agg1 = 0.f, agg2 = 0.f, agg3 = 0.f;
    const int w = ln >> 3, shb = (ln & 7) * 4;

    for (int ch = 0; ch < nchunk; ++ch) {
        int base = ch << 7;
        __syncthreads();
        #pragma unroll
        for (int rep = 0; rep < 4; ++rep) {
            int i = base + rep * 32 + ln;
            if (i < cnt) {
                int e = beg + i;
                int s = src_s[e];
                attr_l[ns][rep * 32 + ln] = attr_s[e];
                *(uint4*)&words_l[ns][rep * 32 + ln][0] =
                    *(const uint4*)&sb_cur[(size_t)s * 4];
            }
        }
        __syncthreads();
        int lim = min(128, cnt - base);
        for (int i = 0; i < lim; ++i) {
            uint32_t u = words_l[ns][i][w];
            float a = attr_l[ns][i];
            uint32_t bits = (u >> shb) & 0xFu;
            agg0 = __fadd_rn(agg0, (bits & 1u) ? a : 0.0f);
            agg1 = __fadd_rn(agg1, (bits & 2u) ? a : 0.0f);
            agg2 = __fadd_rn(agg2, (bits & 4u) ? a : 0.0f);
            agg3 = __fadd_rn(agg3, (bits & 8u) ? a : 0.0f);
        }
    }

    const size_t idx = (size_t)n * HID + ln * 4;
    float4 h4 = *(const float4*)&h[idx];
    if (t0) {
        const int jb = ln * 4;
        float hq[4] = {h4.x, h4.y, h4.z, h4.w};
        #pragma unroll
        for (int q = 0; q < 4; ++q) {
            float mn = dec_f(mn_e[jb + q]);
            float mx = dec_f(mx_e[jb + q]);
            float d2 = __fadd_rn(__fsub_rn(mx, mn), 1e-6f);
            hq[q] = __fdiv_rn(__fsub_rn(hq[q], mn), d2);
        }
        h4 = make_float4(hq[0], hq[1], hq[2], hq[3]);
        *(float4*)&h[idx] = h4;
    }
    float4 v4;
    unsigned int rcu;
    if (t0) { v4 = make_float4(0.f, 0.f, 0.f, 0.f); rcu = 0u; }
    else    { v4 = *(const float4*)&v[idx]; rcu = *(const unsigned int*)&refc[idx]; }

    float hv[4]  = {h4.x, h4.y, h4.z, h4.w};
    float vv[4]  = {v4.x, v4.y, v4.z, v4.w};
    float ag[4]  = {agg0, agg1, agg2, agg3};
    float vf[4], sf[4];
    unsigned int rcn = 0u, nib = 0u;
    #pragma unroll
    for (int q = 0; q < 4; ++q) {
        float vn = __fadd_rn(__fadd_rn(__fmul_rn(0.8f, vv[q]), hv[q]), ag[q]);
        unsigned int rc = (rcu >> (8 * q)) & 0xFFu;
        bool spk = (vn >= 0.5f) && (rc == 0u);
        vf[q] = spk ? 0.0f : vn;
        sf[q] = spk ? 1.0f : 0.0f;
        unsigned int rnew = spk ? 2u : (rc > 0u ? rc - 1u : 0u);
        rcn |= rnew << (8 * q);
        nib |= (spk ? 1u : 0u) << q;
    }
    *(float4*)&v[idx] = make_float4(vf[0], vf[1], vf[2], vf[3]);
    *(unsigned int*)&refc[idx] = rcn;
    *(float4*)&out_spk[idx] = make_float4(sf[0], sf[1], sf[2], sf[3]);
    if (is_last) {
        *(float4*)&out_fus[idx] = make_float4(
            __fadd_rn(hv[0], __fmul_rn(0.5f, vf[0])),
            __fadd_rn(hv[1], __fmul_rn(0.5f, vf[1])),
            __fadd_rn(hv[2], __fmul_rn(0.5f, vf[2])),
            __fadd_rn(hv[3], __fmul_rn(0.5f, vf[3])));
    }
    atomicOr(&sbw[ns * 4 + w], nib << shb);
    __syncthreads();
    if (tid < 16)
        sb_nxt[(size_t)(nb + (tid >> 2)) * 4 + (tid & 3)] = sbw[tid];
}

// ---------- fused 8-step LIF: persistent cooperative kernel ----------
// 758 blocks x 256 threads at 3 blocks/CU (capacity 768 -> slack). Each block
// owns 66 nodes; h/v/ref live in registers across steps; CSR edges staged
// once in LDS; spike bitmask exchanged via global + grid.sync().
#define NPB 66
#define ECAP 2048
#define NSLOT 9
#define GRID_F ((N_NODES + NPB - 1) / NPB)   // 758
__global__ __launch_bounds__(256, 3) void k_fused(
    const int* __restrict__ row_ptr,
    const int* __restrict__ src_s,
    const float* __restrict__ attr_s,
    uint32_t* __restrict__ sbA,
    uint32_t* __restrict__ sbB,
    const float* __restrict__ h_raw,
    const unsigned int* __restrict__ mn_e,
    const unsigned int* __restrict__ mx_e,
    float* __restrict__ out)
{
    __shared__ int      lrp[NPB + 1];
    __shared__ int      ed_src[ECAP];
    __shared__ float    ed_attr[ECAP];
    __shared__ uint32_t sbw[NPB][4];

    cg::grid_group grid = cg::this_grid();

    const int tid = threadIdx.x;
    const int g   = tid >> 5;              // node group 0..7
    const int ln  = tid & 31;              // features 4ln..4ln+3
    const int n0  = blockIdx.x * NPB;
    const int ncnt = (N_NODES - n0 < NPB) ? (N_NODES - n0) : NPB;
    const int nwords = (ncnt > 0 ? ncnt : 0) * 4;
    const int w = ln >> 3, shb = (ln & 7) * 4;
    const size_t NH = (size_t)N_NODES * HID;

    int ebase = 0; bool inlds = false;
    if (ncnt > 0) {
        if (tid <= ncnt) lrp[tid] = row_ptr[n0 + tid];
        __syncthreads();
        ebase = lrp[0];
        int etot = lrp[ncnt] - ebase;
        inlds = (etot <= ECAP);
        if (inlds) {
            for (int i = tid; i < etot; i += 256) {
                ed_src[i]  = src_s[ebase + i];
                ed_attr[i] = attr_s[ebase + i];
            }
        }
    }
    __syncthreads();

    uint4 mnu = *(const uint4*)&mn_e[ln * 4];
    uint4 mxu = *(const uint4*)&mx_e[ln * 4];
    float mn0 = dec_f(mnu.x), mn1 = dec_f(mnu.y), mn2 = dec_f(mnu.z), mn3 = dec_f(mnu.w);
    float dd0 = __fadd_rn(__fsub_rn(dec_f(mxu.x), mn0), 1e-6f);
    float dd1 = __fadd_rn(__fsub_rn(dec_f(mxu.y), mn1), 1e-6f);
    float dd2 = __fadd_rn(__fsub_rn(dec_f(mxu.z), mn2), 1e-6f);
    float dd3 = __fadd_rn(__fsub_rn(dec_f(mxu.w), mn3), 1e-6f);

    float4 hs[NSLOT], vs[NSLOT];
    uint32_t rcs[NSLOT];
    #pragma unroll
    for (int s = 0; s < NSLOT; ++s) {
        hs[s] = make_float4(0.f, 0.f, 0.f, 0.f);
        vs[s] = make_float4(0.f, 0.f, 0.f, 0.f);
        rcs[s] = 0u;
        int m = s * 8 + g;
        if (m < ncnt) {
            size_t idx = (size_t)(n0 + m) * HID + ln * 4;
            float4 t = *(const float4*)&h_raw[idx];
            t.x = __fdiv_rn(__fsub_rn(t.x, mn0), dd0);
            t.y = __fdiv_rn(__fsub_rn(t.y, mn1), dd1);
            t.z = __fdiv_rn(__fsub_rn(t.z, mn2), dd2);
            t.w = __fdiv_rn(__fsub_rn(t.w, mn3), dd3);
            hs[s] = t;
        }
    }

    for (int t = 0; t < T_STEPS; ++t) {
        const uint32_t* cur = (t & 1) ? sbB : sbA;
        uint32_t*       nxt = (t & 1) ? sbA : sbB;
        if (t > 0) {
            __threadfence();
            grid.sync();
            __threadfence();
        }
        for (int i2 = tid; i2 < nwords; i2 += 256) ((uint32_t*)sbw)[i2] = 0u;
        __syncthreads();

        #pragma unroll 1
        for (int s = 0; s < NSLOT; ++s) {
            int m = s * 8 + g;
            if (m >= ncnt) continue;
            int lb, le;
            if (inlds) { lb = lrp[m] - ebase; le = lrp[m + 1] - ebase; }
            else       { lb = lrp[m];         le = lrp[m + 1]; }
            float ag0 = 0.f, ag1 = 0.f, ag2 = 0.f, ag3 = 0.f;
            int i = lb;
            if (inlds) {
                for (; i + 3 < le; i += 4) {           // ascending edge order
                    int e0 = ed_src[i], e1 = ed_src[i+1], e2 = ed_src[i+2], e3 = ed_src[i+3];
                    uint32_t u0 = cur[(size_t)e0 * 4 + w];
                    uint32_t u1 = cur[(size_t)e1 * 4 + w];
                    uint32_t u2 = cur[(size_t)e2 * 4 + w];
                    uint32_t u3 = cur[(size_t)e3 * 4 + w];
                    float a0 = ed_attr[i], a1 = ed_attr[i+1], a2 = ed_attr[i+2], a3 = ed_attr[i+3];
                    uint32_t b0 = (u0 >> shb) & 0xFu, b1 = (u1 >> shb) & 0xFu;
                    uint32_t b2 = (u2 >> shb) & 0xFu, b3 = (u3 >> shb) & 0xFu;
                    ag0 = __fadd_rn(ag0, (b0 & 1u) ? a0 : 0.f);
                    ag1 = __fadd_rn(ag1, (b0 & 2u) ? a0 : 0.f);
                    ag2 = __fadd_rn(ag2, (b0 & 4u) ? a0 : 0.f);
                    ag3 = __fadd_rn(ag3, (b0 & 8u) ? a0 : 0.f);
                    ag0 = __fadd_rn(ag0, (b1 & 1u) ? a1 : 0.f);
                    ag1 = __fadd_rn(ag1, (b1 & 2u) ? a1 : 0.f);
                    ag2 = __fadd_rn(ag2, (b1 & 4u) ? a1 : 0.f);
                    ag3 = __fadd_rn(ag3, (b1 & 8u) ? a1 : 0.f);
                    ag0 = __fadd_rn(ag0, (b2 & 1u) ? a2 : 0.f);
                    ag1 = __fadd_rn(ag1, (b2 & 2u) ? a2 : 0.f);
                    ag2 = __fadd_rn(ag2, (b2 & 4u) ? a2 : 0.f);
                    ag3 = __fadd_rn(ag3, (b2 & 8u) ? a2 : 0.f);
                    ag0 = __fadd_rn(ag0, (b3 & 1u) ? a3 : 0.f);
                    ag1 = __fadd_rn(ag1, (b3 & 2u) ? a3 : 0.f);
                    ag2 = __fadd_rn(ag2, (b3 & 4u) ? a3 : 0.f);
                    ag3 = __fadd_rn(ag3, (b3 & 8u) ? a3 : 0.f);
                }
                for (; i < le; ++i) {
                    int e0 = ed_src[i];
                    uint32_t u0 = cur[(size_t)e0 * 4 + w];
                    float a0 = ed_attr[i];
                    uint32_t b0 = (u0 >> shb) & 0xFu;
                    ag0 = __fadd_rn(ag0, (b0 & 1u) ? a0 : 0.f);
                    ag1 = __fadd_rn(ag1, (b0 & 2u) ? a0 : 0.f);
                    ag2 = __fadd_rn(ag2, (b0 & 4u) ? a0 : 0.f);
                    ag3 = __fadd_rn(ag3, (b0 & 8u) ? a0 : 0.f);
                }
            } else {
                for (; i < le; ++i) {
                    int e0 = src_s[i];
                    uint32_t u0 = cur[(size_t)e0 * 4 + w];
                    float a0 = attr_s[i];
                    uint32_t b0 = (u0 >> shb) & 0xFu;
                    ag0 = __fadd_rn(ag0, (b0 & 1u) ? a0 : 0.f);
                    ag1 = __fadd_rn(ag1, (b0 & 2u) ? a0 : 0.f);
                    ag2 = __fadd_rn(ag2, (b0 & 4u) ? a0 : 0.f);
                    ag3 = __fadd_rn(ag3, (b0 & 8u) ? a0 : 0.f);
                }
            }

            float hv[4] = {hs[s].x, hs[s].y, hs[s].z, hs[s].w};
            float vv[4] = {vs[s].x, vs[s].y, vs[s].z, vs[s].w};
            float ag[4] = {ag0, ag1, ag2, ag3};
            float vf[4], sf[4];
            uint32_t rcu = rcs[s], rcn = 0u, nib = 0u;
            #pragma unroll
            for (int q = 0; q < 4; ++q) {
                float vn = __fadd_rn(__fadd_rn(__fmul_rn(0.8f, vv[q]), hv[q]), ag[q]);
                uint32_t rc = (rcu >> (8 * q)) & 0xFFu;
                bool spk = (vn >= 0.5f) && (rc == 0u);
                vf[q] = spk ? 0.0f : vn;
                sf[q] = spk ? 1.0f : 0.0f;
                uint32_t rnew = spk ? 2u : (rc > 0u ? rc - 1u : 0u);
                rcn |= rnew << (8 * q);
                nib |= (spk ? 1u : 0u) << q;
            }
            vs[s] = make_float4(vf[0], vf[1], vf[2], vf[3]);
            rcs[s] = rcn;
            size_t idx = (size_t)(n0 + m) * HID + ln * 4;
            *(float4*)&out[NH + (size_t)t * NH + idx] =
                make_float4(sf[0], sf[1], sf[2], sf[3]);
            if (t == T_STEPS - 1) {
                *(float4*)&out[idx] = make_float4(
                    __fadd_rn(hv[0], __fmul_rn(0.5f, vf[0])),
                    __fadd_rn(hv[1], __fmul_rn(0.5f, vf[1])),
                    __fadd_rn(hv[2], __fmul_rn(0.5f, vf[2])),
                    __fadd_rn(hv[3], __fmul_rn(0.5f, vf[3])));
            }
            atomicOr(&sbw[m][w], nib << shb);
        }
        __syncthreads();
        for (int i2 = tid; i2 < nwords; i2 += 256)
            nxt[(size_t)n0 * 4 + i2] = ((uint32_t*)sbw)[i2];
    }
}

extern "C" void kernel_launch(void* const* d_in, const int* in_sizes, int n_in,
                              void* d_out, int out_size, void* d_ws, size_t ws_size,
                              hipStream_t stream) {
    const float* x          = (const float*)d_in[0];
    const int*   spike_node = (const int*)  d_in[1];
    const int*   edge_index = (const int*)  d_in[2];   // [2][E]
    const float* edge_attr  = (const float*)d_in[4];
    const float* W          = (const float*)d_in[5];
    const float* b          = (const float*)d_in[6];
    float* out = (float*)d_out;

    const int* src = edge_index;
    const int* dst = edge_index + N_EDGES;

    char* wsp = (char*)d_ws;
    auto alloc = [&](size_t bytes) {
        char* p = wsp;
        wsp += (bytes + 255) & ~(size_t)255;
        return p;
    };
    float*         h        = (float*)        alloc((size_t)N_NODES * HID * 4);
    float*         v        = (float*)        alloc((size_t)N_NODES * HID * 4);
    unsigned char* refc     = (unsigned char*)alloc((size_t)N_NODES * HID);
    uint32_t*      sbA      = (uint32_t*)     alloc((size_t)N_NODES * 16);
    uint32_t*      sbB      = (uint32_t*)     alloc((size_t)N_NODES * 16);
    int*           counts   = (int*)          alloc((size_t)N_NODES * 4);
    int*           cursor   = (int*)          alloc((size_t)N_NODES * 4);
    int*           row_tmp  = (int*)          alloc((size_t)N_NODES * 4);
    int*           row_ptr  = (int*)          alloc((size_t)(N_NODES + 1) * 4);
    int*           blocksum = (int*)          alloc(256 * 4);
    int*           blockoff = (int*)          alloc(256 * 4);
    int*           eid      = (int*)          alloc((size_t)N_EDGES * 4);
    int*           src_s    = (int*)          alloc((size_t)N_EDGES * 4);
    float*         attr_s   = (float*)        alloc((size_t)N_EDGES * 4);
    unsigned int*  mn_e     = (unsigned int*) alloc(HID * 4);
    unsigned int*  mx_e     = (unsigned int*) alloc(HID * 4);

    hipMemsetAsync(counts, 0x00, (size_t)N_NODES * 4, stream);
    hipMemsetAsync(cursor, 0x00, (size_t)N_NODES * 4, stream);
    hipMemsetAsync(mn_e,   0xFF, HID * 4, stream);
    hipMemsetAsync(mx_e,   0x00, HID * 4, stream);

    const int NB = (N_NODES + 255) / 256;   // 196
    const int EB = (N_EDGES + 255) / 256;

    k_count<<<EB, 256, 0, stream>>>(dst, counts);
    k_scan1<<<NB, 256, 0, stream>>>(counts, row_tmp, blocksum);
    k_scan2<<<1, 64, 0, stream>>>(blocksum, blockoff, NB, row_ptr);
    k_scan3<<<NB, 256, 0, stream>>>(row_tmp, blockoff, row_ptr);
    k_fill<<<EB, 256, 0, stream>>>(dst, src, edge_attr, row_ptr, cursor, eid, src_s, attr_s);
    k_bsort<<<N_NODES / 4, 256, 0, stream>>>(row_ptr, eid, src_s, attr_s);

    k_gemm<<<(N_NODES + 63) / 64, 256, 0, stream>>>(x, W, b, h, mn_e, mx_e);
    k_init_bits<<<NB, 256, 0, stream>>>(spike_node, sbA);

    const size_t NH = (size_t)N_NODES * HID;

    // ---- coop path if provably co-resident; else R2-verified fallback ----
    int maxB = 0;
    hipError_t qerr = hipOccupancyMaxActiveBlocksPerMultiprocessor(&maxB, k_fused, 256, 0);
    bool coop_done = false;
    if (qerr == hipSuccess && maxB * 256 >= GRID_F) {
        const int*          a_row  = row_ptr;
        const int*          a_src  = src_s;
        const float*        a_attr = attr_s;
        uint32_t*           a_sbA  = sbA;
        uint32_t*           a_sbB  = sbB;
        const float*        a_h    = h;
        const unsigned int* a_mn   = mn_e;
        const unsigned int* a_mx   = mx_e;
        float*              a_out  = out;
        void* kargs[] = { (void*)&a_row, (void*)&a_src, (void*)&a_attr,
                          (void*)&a_sbA, (void*)&a_sbB, (void*)&a_h,
                          (void*)&a_mn,  (void*)&a_mx,  (void*)&a_out };
        hipError_t lerr = hipLaunchCooperativeKernel((const void*)k_fused,
                                                     dim3(GRID_F), dim3(256),
                                                     kargs, 0, stream);
        coop_done = (lerr == hipSuccess);
    }
    if (!coop_done) {
        for (int t = 0; t < T_STEPS; ++t) {
            uint32_t* cur = (t & 1) ? sbB : sbA;
            uint32_t* nxt = (t & 1) ? sbA : sbB;
            k_step<<<N_NODES / 4, 128, 0, stream>>>(row_ptr, src_s, attr_s, cur, nxt,
                                                    h, v, refc, mn_e, mx_e,
                                                    out + NH + (size_t)t * NH,
                                                    out, (t == 0) ? 1 : 0,
                                                    (t == T_STEPS - 1) ? 1 : 0);
        }
    }
}

// Round 5
// 637.045 us; speedup vs baseline: 3.6217x; 3.6217x over previous
//
#include <hip/hip_runtime.h>
#include <hip/hip_cooperative_groups.h>
#include <cstdint>

namespace cg = cooperative_groups;

#define N_NODES 50000
#define N_EDGES 800000
#define IN_DIM  256
#define HID     128
#define T_STEPS 8

// ---------- float <-> orderable uint encoding for atomic min/max ----------
static __device__ __forceinline__ unsigned int enc_f(float f) {
    unsigned int u = __float_as_uint(f);
    return (u & 0x80000000u) ? ~u : (u | 0x80000000u);
}
static __device__ __forceinline__ float dec_f(unsigned int u) {
    unsigned int b = (u & 0x80000000u) ? (u ^ 0x80000000u) : ~u;
    return __uint_as_float(b);
}

// ---------- CSR build ----------
__global__ void k_count(const int* __restrict__ dst, int* __restrict__ counts) {
    int e = blockIdx.x * blockDim.x + threadIdx.x;
    if (e < N_EDGES) atomicAdd(&counts[dst[e]], 1);
}

__global__ void k_scan1(const int* __restrict__ counts, int* __restrict__ row_tmp,
                        int* __restrict__ blocksum) {
    __shared__ int sh[256];
    int t = threadIdx.x, i = blockIdx.x * 256 + t;
    int c = (i < N_NODES) ? counts[i] : 0;
    sh[t] = c; __syncthreads();
    for (int off = 1; off < 256; off <<= 1) {
        int val = (t >= off) ? sh[t - off] : 0;
        __syncthreads();
        sh[t] += val;
        __syncthreads();
    }
    if (i < N_NODES) row_tmp[i] = sh[t] - c;     // exclusive
    if (t == 255) blocksum[blockIdx.x] = sh[255];
}

__global__ void k_scan2(const int* __restrict__ blocksum, int* __restrict__ blockoff,
                        int nb, int* __restrict__ row_ptr) {
    if (threadIdx.x == 0) {
        int acc = 0;
        for (int b = 0; b < nb; ++b) { blockoff[b] = acc; acc += blocksum[b]; }
        row_ptr[N_NODES] = acc;   // == N_EDGES
    }
}

__global__ void k_scan3(const int* __restrict__ row_tmp, const int* __restrict__ blockoff,
                        int* __restrict__ row_ptr) {
    int i = blockIdx.x * blockDim.x + threadIdx.x;
    if (i < N_NODES) row_ptr[i] = row_tmp[i] + blockoff[i >> 8];
}

// fill CSR slots directly with the (eid, src, attr) triple (arbitrary order)
__global__ void k_fill(const int* __restrict__ dst, const int* __restrict__ src,
                       const float* __restrict__ attr,
                       const int* __restrict__ row_ptr, int* __restrict__ cursor,
                       int* __restrict__ eid, int* __restrict__ src_s,
                       float* __restrict__ attr_s) {
    int e = blockIdx.x * blockDim.x + threadIdx.x;
    if (e >= N_EDGES) return;
    int d = dst[e];
    int p = row_ptr[d] + atomicAdd(&cursor[d], 1);
    eid[p]    = e;
    src_s[p]  = src[e];
    attr_s[p] = attr[e];
}

// wave-wide bitonic sort per node by eid: restores np.add.at ascending order
__global__ __launch_bounds__(256) void k_bsort(const int* __restrict__ row_ptr,
                                               int* __restrict__ eid,
                                               int* __restrict__ src_s,
                                               float* __restrict__ attr_s) {
    int node = blockIdx.x * 4 + (threadIdx.x >> 6);
    int l = threadIdx.x & 63;
    int beg = row_ptr[node], end = row_ptr[node + 1], cnt = end - beg;
    if (cnt <= 1) return;
    if (cnt <= 64) {
        int key = 0x7FFFFFFF, sv = 0; float av = 0.f;
        if (l < cnt) { key = eid[beg + l]; sv = src_s[beg + l]; av = attr_s[beg + l]; }
        #pragma unroll
        for (int k = 2; k <= 64; k <<= 1) {
            for (int j = k >> 1; j > 0; j >>= 1) {
                int   pk = __shfl_xor(key, j);
                int   ps = __shfl_xor(sv, j);
                float pa = __shfl_xor(av, j);
                bool lower = (l & j) == 0;
                bool asc   = (l & k) == 0;
                bool take_min = (lower == asc);
                bool take = take_min ? (pk < key) : (pk > key);
                if (take) { key = pk; sv = ps; av = pa; }
            }
        }
        if (l < cnt) { eid[beg + l] = key; src_s[beg + l] = sv; attr_s[beg + l] = av; }
    } else if (l == 0) {
        for (int i = beg + 1; i < end; ++i) {
            int ke = eid[i]; int ks = src_s[i]; float ka = attr_s[i];
            int m = i - 1;
            while (m >= beg && eid[m] > ke) {
                eid[m+1] = eid[m]; src_s[m+1] = src_s[m]; attr_s[m+1] = attr_s[m]; --m;
            }
            eid[m+1] = ke; src_s[m+1] = ks; attr_s[m+1] = ka;
        }
    }
}

// ---------- tiled GEMM: 64 nodes x 128 feats per block, fused min/max ----------
__global__ __launch_bounds__(256) void k_gemm(const float* __restrict__ x,
                                              const float* __restrict__ W,
                                              const float* __restrict__ b,
                                              float* __restrict__ h,
                                              unsigned int* __restrict__ mn_e,
                                              unsigned int* __restrict__ mx_e) {
    __shared__ float Ws[32 * 128];
    __shared__ float xs[64 * 36];
    __shared__ float red_mn[8 * 128];
    __shared__ float red_mx[8 * 128];
    const int tid = threadIdx.x;
    const int n0 = blockIdx.x * 64;
    const int jt = tid & 31, nt = tid >> 5;
    const int j0 = jt * 4;

    float acc[8][4];
    #pragma unroll
    for (int a = 0; a < 8; ++a)
        #pragma unroll
        for (int c = 0; c < 4; ++c) acc[a][c] = 0.0f;

    const int ldn = tid >> 2;
    const int kq  = (tid & 3) * 8;
    const int xrow = (n0 + ldn < N_NODES) ? (n0 + ldn) : (N_NODES - 1);
    const float* xg = x + (size_t)xrow * IN_DIM;

    for (int kc = 0; kc < IN_DIM; kc += 32) {
        __syncthreads();
        float4 xa = *(const float4*)(xg + kc + kq);
        float4 xb = *(const float4*)(xg + kc + kq + 4);
        *(float4*)&xs[ldn * 36 + kq]     = xa;
        *(float4*)&xs[ldn * 36 + kq + 4] = xb;
        #pragma unroll
        for (int p = 0; p < 4; ++p) {
            int r = nt + p * 8;
            *(float4*)&Ws[r * 128 + j0] =
                *(const float4*)(W + (size_t)(kc + r) * HID + j0);
        }
        __syncthreads();
        const float* xbase = &xs[nt * 8 * 36];
        #pragma unroll 4
        for (int k = 0; k < 32; ++k) {
            float4 wf = *(const float4*)&Ws[k * 128 + j0];
            #pragma unroll
            for (int ni = 0; ni < 8; ++ni) {
                float xv = xbase[ni * 36 + k];
                acc[ni][0] = __fmaf_rn(xv, wf.x, acc[ni][0]);
                acc[ni][1] = __fmaf_rn(xv, wf.y, acc[ni][1]);
                acc[ni][2] = __fmaf_rn(xv, wf.z, acc[ni][2]);
                acc[ni][3] = __fmaf_rn(xv, wf.w, acc[ni][3]);
            }
        }
    }

    float4 bv = *(const float4*)(b + j0);
    float lmn[4], lmx[4];
    #pragma unroll
    for (int c = 0; c < 4; ++c) { lmn[c] = INFINITY; lmx[c] = -INFINITY; }
    #pragma unroll
    for (int ni = 0; ni < 8; ++ni) {
        acc[ni][0] = __fadd_rn(acc[ni][0], bv.x);
        acc[ni][1] = __fadd_rn(acc[ni][1], bv.y);
        acc[ni][2] = __fadd_rn(acc[ni][2], bv.z);
        acc[ni][3] = __fadd_rn(acc[ni][3], bv.w);
        #pragma unroll
        for (int c = 0; c < 4; ++c) {
            lmn[c] = fminf(lmn[c], acc[ni][c]);
            lmx[c] = fmaxf(lmx[c], acc[ni][c]);
        }
    }
    #pragma unroll
    for (int c = 0; c < 4; ++c) {
        red_mn[nt * 128 + j0 + c] = lmn[c];
        red_mx[nt * 128 + j0 + c] = lmx[c];
    }
    __syncthreads();
    if (tid < 128) {
        float mnv = red_mn[tid], mxv = red_mx[tid];
        #pragma unroll
        for (int r = 1; r < 8; ++r) {
            mnv = fminf(mnv, red_mn[r * 128 + tid]);
            mxv = fmaxf(mxv, red_mx[r * 128 + tid]);
        }
        atomicMin(&mn_e[tid], enc_f(mnv));
        atomicMax(&mx_e[tid], enc_f(mxv));
    }
    #pragma unroll
    for (int ni = 0; ni < 8; ++ni) {
        int n = n0 + nt * 8 + ni;
        if (n < N_NODES)
            *(float4*)&h[(size_t)n * HID + j0] =
                make_float4(acc[ni][0], acc[ni][1], acc[ni][2], acc[ni][3]);
    }
}

// ---------- init spike bitmask ----------
__global__ void k_init_bits(const int* __restrict__ spike_node, uint32_t* __restrict__ sb) {
    int n = blockIdx.x * blockDim.x + threadIdx.x;
    if (n >= N_NODES) return;
    uint32_t f = spike_node[n] ? 0xFFFFFFFFu : 0u;
    sb[(size_t)n * 4 + 0] = f;
    sb[(size_t)n * 4 + 1] = f;
    sb[(size_t)n * 4 + 2] = f;
    sb[(size_t)n * 4 + 3] = f;
}

// ---------- fallback per-step kernel (verified in R2) ----------
__global__ __launch_bounds__(128) void k_step(const int* __restrict__ row_ptr,
                                              const int* __restrict__ src_s,
                                              const float* __restrict__ attr_s,
                                              const uint32_t* __restrict__ sb_cur,
                                              uint32_t* __restrict__ sb_nxt,
                                              float* __restrict__ h,
                                              float* __restrict__ v,
                                              unsigned char* __restrict__ refc,
                                              const unsigned int* __restrict__ mn_e,
                                              const unsigned int* __restrict__ mx_e,
                                              float* __restrict__ out_spk,
                                              float* __restrict__ out_fus,
                                              int t0, int is_last) {
    __shared__ float    attr_l[4][128];
    __shared__ uint32_t words_l[4][128][4];
    __shared__ uint32_t sbw[16];
    __shared__ int      rp[5];

    const int tid = threadIdx.x;
    const int ns = tid >> 5, ln = tid & 31;
    const int nb = blockIdx.x * 4;
    const int n  = nb + ns;

    if (tid < 16) sbw[tid] = 0;
    if (tid < 5)  rp[tid] = row_ptr[nb + tid];
    __syncthreads();

    const int beg = rp[ns], cnt = rp[ns + 1] - beg;
    int cmax = 0;
    #pragma unroll
    for (int q = 0; q < 4; ++q) cmax = max(cmax, rp[q + 1] - rp[q]);
    const int nchunk = (cmax + 127) >> 7;

    float agg0 = 0.f, agg1 = 0.f, agg2 = 0.f, agg3 = 0.f;
    const int w = ln >> 3, shb = (ln & 7) * 4;

    for (int ch = 0; ch < nchunk; ++ch) {
        int base = ch << 7;
        __syncthreads();
        #pragma unroll
        for (int rep = 0; rep < 4; ++rep) {
            int i = base + rep * 32 + ln;
            if (i < cnt) {
                int e = beg + i;
                int s = src_s[e];
                attr_l[ns][rep * 32 + ln] = attr_s[e];
                *(uint4*)&words_l[ns][rep * 32 + ln][0] =
                    *(const uint4*)&sb_cur[(size_t)s * 4];
            }
        }
        __syncthreads();
        int lim = min(128, cnt - base);
        for (int i = 0; i < lim; ++i) {
            uint32_t u = words_l[ns][i][w];
            float a = attr_l[ns][i];
            uint32_t bits = (u >> shb) & 0xFu;
            agg0 = __fadd_rn(agg0, (bits & 1u) ? a : 0.0f);
            agg1 = __fadd_rn(agg1, (bits & 2u) ? a : 0.0f);
            agg2 = __fadd_rn(agg2, (bits & 4u) ? a : 0.0f);
            agg3 = __fadd_rn(agg3, (bits & 8u) ? a : 0.0f);
        }
    }

    const size_t idx = (size_t)n * HID + ln * 4;
    float4 h4 = *(const float4*)&h[idx];
    if (t0) {
        const int jb = ln * 4;
        float hq[4] = {h4.x, h4.y, h4.z, h4.w};
        #pragma unroll
        for (int q = 0; q < 4; ++q) {
            float mn = dec_f(mn_e[jb + q]);
            float mx = dec_f(mx_e[jb + q]);
            float d2 = __fadd_rn(__fsub_rn(mx, mn), 1e-6f);
            hq[q] = __fdiv_rn(__fsub_rn(hq[q], mn), d2);
        }
        h4 = make_float4(hq[0], hq[1], hq[2], hq[3]);
        *(float4*)&h[idx] = h4;
    }
    float4 v4;
    unsigned int rcu;
    if (t0) { v4 = make_float4(0.f, 0.f, 0.f, 0.f); rcu = 0u; }
    else    { v4 = *(const float4*)&v[idx]; rcu = *(const unsigned int*)&refc[idx]; }

    float hv[4]  = {h4.x, h4.y, h4.z, h4.w};
    float vv[4]  = {v4.x, v4.y, v4.z, v4.w};
    float ag[4]  = {agg0, agg1, agg2, agg3};
    float vf[4], sf[4];
    unsigned int rcn = 0u, nib = 0u;
    #pragma unroll
    for (int q = 0; q < 4; ++q) {
        float vn = __fadd_rn(__fadd_rn(__fmul_rn(0.8f, vv[q]), hv[q]), ag[q]);
        unsigned int rc = (rcu >> (8 * q)) & 0xFFu;
        bool spk = (vn >= 0.5f) && (rc == 0u);
        vf[q] = spk ? 0.0f : vn;
        sf[q] = spk ? 1.0f : 0.0f;
        unsigned int rnew = spk ? 2u : (rc > 0u ? rc - 1u : 0u);
        rcn |= rnew << (8 * q);
        nib |= (spk ? 1u : 0u) << q;
    }
    *(float4*)&v[idx] = make_float4(vf[0], vf[1], vf[2], vf[3]);
    *(unsigned int*)&refc[idx] = rcn;
    *(float4*)&out_spk[idx] = make_float4(sf[0], sf[1], sf[2], sf[3]);
    if (is_last) {
        *(float4*)&out_fus[idx] = make_float4(
            __fadd_rn(hv[0], __fmul_rn(0.5f, vf[0])),
            __fadd_rn(hv[1], __fmul_rn(0.5f, vf[1])),
            __fadd_rn(hv[2], __fmul_rn(0.5f, vf[2])),
            __fadd_rn(hv[3], __fmul_rn(0.5f, vf[3])));
    }
    atomicOr(&sbw[ns * 4 + w], nib << shb);
    __syncthreads();
    if (tid < 16)
        sb_nxt[(size_t)(nb + (tid >> 2)) * 4 + (tid & 3)] = sbw[tid];
}

// ---------- fused 8-step LIF: persistent cooperative kernel ----------
// 758 blocks x 256 threads at 3 blocks/CU (capacity 768). Each block owns 66
// nodes; h/v/ref live in REGISTERS across steps (slot loop FULLY UNROLLED —
// `#pragma unroll 1` here caused dynamic indexing -> scratch spill, VGPR=36,
// +420 MB scratch traffic, 1862 us in R4). CSR edges staged once in LDS;
// spike bitmask exchanged via global + grid.sync().
#define NPB 66
#define ECAP 2048
#define NSLOT 9
#define GRID_F ((N_NODES + NPB - 1) / NPB)   // 758
__global__ __launch_bounds__(256, 3) void k_fused(
    const int* __restrict__ row_ptr,
    const int* __restrict__ src_s,
    const float* __restrict__ attr_s,
    uint32_t* __restrict__ sbA,
    uint32_t* __restrict__ sbB,
    const float* __restrict__ h_raw,
    const unsigned int* __restrict__ mn_e,
    const unsigned int* __restrict__ mx_e,
    float* __restrict__ out)
{
    __shared__ int      lrp[NPB + 1];
    __shared__ int      ed_src[ECAP];
    __shared__ float    ed_attr[ECAP];
    __shared__ uint32_t sbw[NPB][4];

    cg::grid_group grid = cg::this_grid();

    const int tid = threadIdx.x;
    const int g   = tid >> 5;              // node group 0..7
    const int ln  = tid & 31;              // features 4ln..4ln+3
    const int n0  = blockIdx.x * NPB;
    const int ncnt = (N_NODES - n0 < NPB) ? (N_NODES - n0) : NPB;
    const int nwords = (ncnt > 0 ? ncnt : 0) * 4;
    const int w = ln >> 3, shb = (ln & 7) * 4;
    const size_t NH = (size_t)N_NODES * HID;

    int ebase = 0; bool inlds = false;
    if (ncnt > 0) {
        if (tid <= ncnt) lrp[tid] = row_ptr[n0 + tid];
        __syncthreads();
        ebase = lrp[0];
        int etot = lrp[ncnt] - ebase;
        inlds = (etot <= ECAP);
        if (inlds) {
            for (int i = tid; i < etot; i += 256) {
                ed_src[i]  = src_s[ebase + i];
                ed_attr[i] = attr_s[ebase + i];
            }
        }
    }
    __syncthreads();

    uint4 mnu = *(const uint4*)&mn_e[ln * 4];
    uint4 mxu = *(const uint4*)&mx_e[ln * 4];
    float mn0 = dec_f(mnu.x), mn1 = dec_f(mnu.y), mn2 = dec_f(mnu.z), mn3 = dec_f(mnu.w);
    float dd0 = __fadd_rn(__fsub_rn(dec_f(mxu.x), mn0), 1e-6f);
    float dd1 = __fadd_rn(__fsub_rn(dec_f(mxu.y), mn1), 1e-6f);
    float dd2 = __fadd_rn(__fsub_rn(dec_f(mxu.z), mn2), 1e-6f);
    float dd3 = __fadd_rn(__fsub_rn(dec_f(mxu.w), mn3), 1e-6f);

    float4 hs[NSLOT], vs[NSLOT];
    uint32_t rcs[NSLOT];
    #pragma unroll
    for (int s = 0; s < NSLOT; ++s) {
        hs[s] = make_float4(0.f, 0.f, 0.f, 0.f);
        vs[s] = make_float4(0.f, 0.f, 0.f, 0.f);
        rcs[s] = 0u;
        int m = s * 8 + g;
        if (m < ncnt) {
            size_t idx = (size_t)(n0 + m) * HID + ln * 4;
            float4 t = *(const float4*)&h_raw[idx];
            t.x = __fdiv_rn(__fsub_rn(t.x, mn0), dd0);
            t.y = __fdiv_rn(__fsub_rn(t.y, mn1), dd1);
            t.z = __fdiv_rn(__fsub_rn(t.z, mn2), dd2);
            t.w = __fdiv_rn(__fsub_rn(t.w, mn3), dd3);
            hs[s] = t;
        }
    }

    for (int t = 0; t < T_STEPS; ++t) {
        const uint32_t* cur = (t & 1) ? sbB : sbA;
        uint32_t*       nxt = (t & 1) ? sbA : sbB;
        if (t > 0) {
            __threadfence();
            grid.sync();
            __threadfence();
        }
        for (int i2 = tid; i2 < nwords; i2 += 256) ((uint32_t*)sbw)[i2] = 0u;
        __syncthreads();

        #pragma unroll
        for (int s = 0; s < NSLOT; ++s) {
            int m = s * 8 + g;
            if (m >= ncnt) continue;
            int lb, le;
            if (inlds) { lb = lrp[m] - ebase; le = lrp[m + 1] - ebase; }
            else       { lb = lrp[m];         le = lrp[m + 1]; }
            float ag0 = 0.f, ag1 = 0.f, ag2 = 0.f, ag3 = 0.f;
            int i = lb;
            if (inlds) {
                for (; i + 3 < le; i += 4) {           // ascending edge order
                    int e0 = ed_src[i], e1 = ed_src[i+1], e2 = ed_src[i+2], e3 = ed_src[i+3];
                    uint32_t u0 = cur[(size_t)e0 * 4 + w];
                    uint32_t u1 = cur[(size_t)e1 * 4 + w];
                    uint32_t u2 = cur[(size_t)e2 * 4 + w];
                    uint32_t u3 = cur[(size_t)e3 * 4 + w];
                    float a0 = ed_attr[i], a1 = ed_attr[i+1], a2 = ed_attr[i+2], a3 = ed_attr[i+3];
                    uint32_t b0 = (u0 >> shb) & 0xFu, b1 = (u1 >> shb) & 0xFu;
                    uint32_t b2 = (u2 >> shb) & 0xFu, b3 = (u3 >> shb) & 0xFu;
                    ag0 = __fadd_rn(ag0, (b0 & 1u) ? a0 : 0.f);
                    ag1 = __fadd_rn(ag1, (b0 & 2u) ? a0 : 0.f);
                    ag2 = __fadd_rn(ag2, (b0 & 4u) ? a0 : 0.f);
                    ag3 = __fadd_rn(ag3, (b0 & 8u) ? a0 : 0.f);
                    ag0 = __fadd_rn(ag0, (b1 & 1u) ? a1 : 0.f);
                    ag1 = __fadd_rn(ag1, (b1 & 2u) ? a1 : 0.f);
                    ag2 = __fadd_rn(ag2, (b1 & 4u) ? a1 : 0.f);
                    ag3 = __fadd_rn(ag3, (b1 & 8u) ? a1 : 0.f);
                    ag0 = __fadd_rn(ag0, (b2 & 1u) ? a2 : 0.f);
                    ag1 = __fadd_rn(ag1, (b2 & 2u) ? a2 : 0.f);
                    ag2 = __fadd_rn(ag2, (b2 & 4u) ? a2 : 0.f);
                    ag3 = __fadd_rn(ag3, (b2 & 8u) ? a2 : 0.f);
                    ag0 = __fadd_rn(ag0, (b3 & 1u) ? a3 : 0.f);
                    ag1 = __fadd_rn(ag1, (b3 & 2u) ? a3 : 0.f);
                    ag2 = __fadd_rn(ag2, (b3 & 4u) ? a3 : 0.f);
                    ag3 = __fadd_rn(ag3, (b3 & 8u) ? a3 : 0.f);
                }
                for (; i < le; ++i) {
                    int e0 = ed_src[i];
                    uint32_t u0 = cur[(size_t)e0 * 4 + w];
                    float a0 = ed_attr[i];
                    uint32_t b0 = (u0 >> shb) & 0xFu;
                    ag0 = __fadd_rn(ag0, (b0 & 1u) ? a0 : 0.f);
                    ag1 = __fadd_rn(ag1, (b0 & 2u) ? a0 : 0.f);
                    ag2 = __fadd_rn(ag2, (b0 & 4u) ? a0 : 0.f);
                    ag3 = __fadd_rn(ag3, (b0 & 8u) ? a0 : 0.f);
                }
            } else {
                for (; i < le; ++i) {
                    int e0 = src_s[i];
                    uint32_t u0 = cur[(size_t)e0 * 4 + w];
                    float a0 = attr_s[i];
                    uint32_t b0 = (u0 >> shb) & 0xFu;
                    ag0 = __fadd_rn(ag0, (b0 & 1u) ? a0 : 0.f);
                    ag1 = __fadd_rn(ag1, (b0 & 2u) ? a0 : 0.f);
                    ag2 = __fadd_rn(ag2, (b0 & 4u) ? a0 : 0.f);
                    ag3 = __fadd_rn(ag3, (b0 & 8u) ? a0 : 0.f);
                }
            }

            float hv[4] = {hs[s].x, hs[s].y, hs[s].z, hs[s].w};
            float vv[4] = {vs[s].x, vs[s].y, vs[s].z, vs[s].w};
            float ag[4] = {ag0, ag1, ag2, ag3};
            float vf[4], sf[4];
            uint32_t rcu = rcs[s], rcn = 0u, nib = 0u;
            #pragma unroll
            for (int q = 0; q < 4; ++q) {
                float vn = __fadd_rn(__fadd_rn(__fmul_rn(0.8f, vv[q]), hv[q]), ag[q]);
                uint32_t rc = (rcu >> (8 * q)) & 0xFFu;
                bool spk = (vn >= 0.5f) && (rc == 0u);
                vf[q] = spk ? 0.0f : vn;
                sf[q] = spk ? 1.0f : 0.0f;
                uint32_t rnew = spk ? 2u : (rc > 0u ? rc - 1u : 0u);
                rcn |= rnew << (8 * q);
                nib |= (spk ? 1u : 0u) << q;
            }
            vs[s] = make_float4(vf[0], vf[1], vf[2], vf[3]);
            rcs[s] = rcn;
            size_t idx = (size_t)(n0 + m) * HID + ln * 4;
            *(float4*)&out[NH + (size_t)t * NH + idx] =
                make_float4(sf[0], sf[1], sf[2], sf[3]);
            if (t == T_STEPS - 1) {
                *(float4*)&out[idx] = make_float4(
                    __fadd_rn(hv[0], __fmul_rn(0.5f, vf[0])),
                    __fadd_rn(hv[1], __fmul_rn(0.5f, vf[1])),
                    __fadd_rn(hv[2], __fmul_rn(0.5f, vf[2])),
                    __fadd_rn(hv[3], __fmul_rn(0.5f, vf[3])));
            }
            atomicOr(&sbw[m][w], nib << shb);
        }
        __syncthreads();
        for (int i2 = tid; i2 < nwords; i2 += 256)
            nxt[(size_t)n0 * 4 + i2] = ((uint32_t*)sbw)[i2];
    }
}

extern "C" void kernel_launch(void* const* d_in, const int* in_sizes, int n_in,
                              void* d_out, int out_size, void* d_ws, size_t ws_size,
                              hipStream_t stream) {
    const float* x          = (const float*)d_in[0];
    const int*   spike_node = (const int*)  d_in[1];
    const int*   edge_index = (const int*)  d_in[2];   // [2][E]
    const float* edge_attr  = (const float*)d_in[4];
    const float* W          = (const float*)d_in[5];
    const float* b          = (const float*)d_in[6];
    float* out = (float*)d_out;

    const int* src = edge_index;
    const int* dst = edge_index + N_EDGES;

    char* wsp = (char*)d_ws;
    auto alloc = [&](size_t bytes) {
        char* p = wsp;
        wsp += (bytes + 255) & ~(size_t)255;
        return p;
    };
    float*         h        = (float*)        alloc((size_t)N_NODES * HID * 4);
    float*         v        = (float*)        alloc((size_t)N_NODES * HID * 4);
    unsigned char* refc     = (unsigned char*)alloc((size_t)N_NODES * HID);
    uint32_t*      sbA      = (uint32_t*)     alloc((size_t)N_NODES * 16);
    uint32_t*      sbB      = (uint32_t*)     alloc((size_t)N_NODES * 16);
    int*           counts   = (int*)          alloc((size_t)N_NODES * 4);
    int*           cursor   = (int*)          alloc((size_t)N_NODES * 4);
    int*           row_tmp  = (int*)          alloc((size_t)N_NODES * 4);
    int*           row_ptr  = (int*)          alloc((size_t)(N_NODES + 1) * 4);
    int*           blocksum = (int*)          alloc(256 * 4);
    int*           blockoff = (int*)          alloc(256 * 4);
    int*           eid      = (int*)          alloc((size_t)N_EDGES * 4);
    int*           src_s    = (int*)          alloc((size_t)N_EDGES * 4);
    float*         attr_s   = (float*)        alloc((size_t)N_EDGES * 4);
    unsigned int*  mn_e     = (unsigned int*) alloc(HID * 4);
    unsigned int*  mx_e     = (unsigned int*) alloc(HID * 4);

    hipMemsetAsync(counts, 0x00, (size_t)N_NODES * 4, stream);
    hipMemsetAsync(cursor, 0x00, (size_t)N_NODES * 4, stream);
    hipMemsetAsync(mn_e,   0xFF, HID * 4, stream);
    hipMemsetAsync(mx_e,   0x00, HID * 4, stream);

    const int NB = (N_NODES + 255) / 256;   // 196
    const int EB = (N_EDGES + 255) / 256;

    k_count<<<EB, 256, 0, stream>>>(dst, counts);
    k_scan1<<<NB, 256, 0, stream>>>(counts, row_tmp, blocksum);
    k_scan2<<<1, 64, 0, stream>>>(blocksum, blockoff, NB, row_ptr);
    k_scan3<<<NB, 256, 0, stream>>>(row_tmp, blockoff, row_ptr);
    k_fill<<<EB, 256, 0, stream>>>(dst, src, edge_attr, row_ptr, cursor, eid, src_s, attr_s);
    k_bsort<<<N_NODES / 4, 256, 0, stream>>>(row_ptr, eid, src_s, attr_s);

    k_gemm<<<(N_NODES + 63) / 64, 256, 0, stream>>>(x, W, b, h, mn_e, mx_e);
    k_init_bits<<<NB, 256, 0, stream>>>(spike_node, sbA);

    const size_t NH = (size_t)N_NODES * HID;

    // ---- coop path if provably co-resident; else R2-verified fallback ----
    int maxB = 0;
    hipError_t qerr = hipOccupancyMaxActiveBlocksPerMultiprocessor(&maxB, k_fused, 256, 0);
    bool coop_done = false;
    if (qerr == hipSuccess && maxB * 256 >= GRID_F) {
        const int*          a_row  = row_ptr;
        const int*          a_src  = src_s;
        const float*        a_attr = attr_s;
        uint32_t*           a_sbA  = sbA;
        uint32_t*           a_sbB  = sbB;
        const float*        a_h    = h;
        const unsigned int* a_mn   = mn_e;
        const unsigned int* a_mx   = mx_e;
        float*              a_out  = out;
        void* kargs[] = { (void*)&a_row, (void*)&a_src, (void*)&a_attr,
                          (void*)&a_sbA, (void*)&a_sbB, (void*)&a_h,
                          (void*)&a_mn,  (void*)&a_mx,  (void*)&a_out };
        hipError_t lerr = hipLaunchCooperativeKernel((const void*)k_fused,
                                                     dim3(GRID_F), dim3(256),
                                                     kargs, 0, stream);
        coop_done = (lerr == hipSuccess);
    }
    if (!coop_done) {
        for (int t = 0; t < T_STEPS; ++t) {
            uint32_t* cur = (t & 1) ? sbB : sbA;
            uint32_t* nxt = (t & 1) ? sbA : sbB;
            k_step<<<N_NODES / 4, 128, 0, stream>>>(row_ptr, src_s, attr_s, cur, nxt,
                                                    h, v, refc, mn_e, mx_e,
                                                    out + NH + (size_t)t * NH,
                                                    out, (t == 0) ? 1 : 0,
                                                    (t == T_STEPS - 1) ? 1 : 0);
        }
    }
}